// Round 1
// baseline (308.908 us; speedup 1.0000x reference)
//
#include <hip/hip_runtime.h>
#include <stdint.h>

#define LOG2E 1.44269504088896340736f

typedef __bf16 v8bf __attribute__((ext_vector_type(8)));
typedef float f32x4 __attribute__((ext_vector_type(4)));

// ---------- helpers ----------
__device__ __forceinline__ unsigned short f2bf(float f) {
  union { float f; uint32_t u; } v; v.f = f;
  uint32_t u = v.u;
  uint32_t r = (u + 0x7FFFu + ((u >> 16) & 1u)) >> 16;   // RN-even
  return (unsigned short)r;
}
__device__ __forceinline__ float bf2f(unsigned short h) {
  union { uint32_t u; float f; } v; v.u = ((uint32_t)h) << 16;
  return v.f;
}
__device__ __forceinline__ void gll16(const void* g, void* l) {
  __builtin_amdgcn_global_load_lds(
      (const __attribute__((address_space(1))) unsigned int*)g,
      (__attribute__((address_space(3))) unsigned int*)l, 16, 0, 0);
}

// ---------- prep: x -> [hi | lo | hi]  (4096 x 2304 bf16) ----------
__global__ void prep_a(const float* __restrict__ x, unsigned short* __restrict__ Acat) {
  int n = blockIdx.x * 256 + threadIdx.x;   // 0..767
  int m = blockIdx.y;                       // 0..4095
  float v = x[(size_t)m * 768 + n];
  unsigned short H = f2bf(v);
  unsigned short L = f2bf(v - bf2f(H));
  size_t base = (size_t)m * 2304;
  Acat[base + n] = H;
  Acat[base + 768 + n] = L;
  Acat[base + 1536 + n] = H;
}

// ---------- prep: Wqkv^T cat -> rows n: [Whi | Whi | Wlo] (2304 x 2304 bf16) ----------
__global__ void prep_bqkv(const float* __restrict__ W, unsigned short* __restrict__ BT) {
  int k = blockIdx.x * 256 + threadIdx.x;   // 0..767
  int n = blockIdx.y;                       // 0..2303
  float v = W[(size_t)k * 2304 + n];
  unsigned short H = f2bf(v);
  unsigned short L = f2bf(v - bf2f(H));
  size_t base = (size_t)n * 2304;
  BT[base + k] = H;
  BT[base + 768 + k] = H;
  BT[base + 1536 + k] = L;
}

// ---------- prep: Wout^T single bf16 (768 x 768) ----------
__global__ void prep_wout(const float* __restrict__ W, unsigned short* __restrict__ BT) {
  int k = blockIdx.x * 256 + threadIdx.x;   // 0..767
  int n = blockIdx.y;                       // 0..767
  BT[(size_t)n * 768 + k] = f2bf(W[(size_t)k * 768 + n]);
}

// ---------- GEMM: C[M,N] = A[M,K](bf16) * B^T[N,K](bf16) + bias[N], fp32 out ----------
// 128x128 tile, BK=32, 256 threads (4 waves, each 64x64), mfma_f32_16x16x32_bf16
__global__ __launch_bounds__(256) void gemm_bf16_128(
    const unsigned short* __restrict__ A, const unsigned short* __restrict__ B,
    const float* __restrict__ bias, float* __restrict__ C,
    int M, int N, int K) {
  __shared__ unsigned short As[128 * 32];
  __shared__ unsigned short Bs[128 * 32];
  const int t = threadIdx.x;
  const int m0 = blockIdx.y * 128, n0 = blockIdx.x * 128;
  const int w = t >> 6, l = t & 63;
  const int wm = (w >> 1) * 64, wn = (w & 1) * 64;
  const int lr = l & 15, lg = l >> 4;
  f32x4 acc[4][4] = {};
  const int nk = K >> 5;
  for (int kt = 0; kt < nk; ++kt) {
    const int k0 = kt << 5;
    {
      const int c0 = t, c1 = t + 256;
      gll16(A + (size_t)(m0 + (c0 >> 2)) * K + k0 + ((c0 & 3) << 3), &As[c0 * 8]);
      gll16(A + (size_t)(m0 + (c1 >> 2)) * K + k0 + ((c1 & 3) << 3), &As[c1 * 8]);
      gll16(B + (size_t)(n0 + (c0 >> 2)) * K + k0 + ((c0 & 3) << 3), &Bs[c0 * 8]);
      gll16(B + (size_t)(n0 + (c1 >> 2)) * K + k0 + ((c1 & 3) << 3), &Bs[c1 * 8]);
    }
    __syncthreads();
    v8bf a[4], b[4];
#pragma unroll
    for (int i = 0; i < 4; i++) {
      a[i] = *(const v8bf*)&As[(wm + i * 16 + lr) * 32 + lg * 8];
      b[i] = *(const v8bf*)&Bs[(wn + i * 16 + lr) * 32 + lg * 8];
    }
#pragma unroll
    for (int i = 0; i < 4; i++)
#pragma unroll
      for (int j = 0; j < 4; j++)
        acc[i][j] = __builtin_amdgcn_mfma_f32_16x16x32_bf16(a[i], b[j], acc[i][j], 0, 0, 0);
    __syncthreads();
  }
#pragma unroll
  for (int i = 0; i < 4; i++) {
#pragma unroll
    for (int j = 0; j < 4; j++) {
      const int col = n0 + wn + j * 16 + lr;
      const float bv = bias[col];
#pragma unroll
      for (int r = 0; r < 4; r++) {
        const int row = m0 + wm + i * 16 + lg * 4 + r;
        C[(size_t)row * N + col] = acc[i][j][r] + bv;
      }
    }
  }
}

// ---------- split qkv fp32 -> Qcat/Kcat (split-bf16, *8 folded into Q), V^T bf16 ----------
// Qcat[bh][p][0:64]=q_hi [64:128]=q_lo [128:192]=q_hi   (A-operand: hi|lo|hi)
// Kcat[bh][p][0:64]=k_hi [64:128]=k_hi [128:192]=k_lo   (B-operand: hi|hi|lo)
// VT[bh][d][p] = bf16(v)
__global__ void split_qkv(const float* __restrict__ qkv,
                          unsigned short* __restrict__ Qc,
                          unsigned short* __restrict__ Kc,
                          unsigned short* __restrict__ VT) {
  int n = blockIdx.x * 256 + threadIdx.x;   // 0..2303
  int m = blockIdx.y;                       // 0..4095
  float val = qkv[(size_t)m * 2304 + n];
  int h = n / 192;
  int j = n - h * 192;
  int b = m >> 11, p = m & 2047;
  int bh = b * 12 + h;
  size_t base = (size_t)bh * 2048 * 192 + (size_t)p * 192;
  if (j < 64) {
    float v8v = val * 8.0f;                 // fold logits *= sqrt(64) (exact: pow2)
    unsigned short H = f2bf(v8v);
    unsigned short L = f2bf(v8v - bf2f(H));
    Qc[base + j] = H; Qc[base + 64 + j] = L; Qc[base + 128 + j] = H;
  } else if (j < 128) {
    int d = j - 64;
    unsigned short H = f2bf(val);
    unsigned short L = f2bf(val - bf2f(H));
    Kc[base + d] = H; Kc[base + 64 + d] = H; Kc[base + 128 + d] = L;
  } else {
    int d = j - 128;
    VT[(size_t)bh * 64 * 2048 + (size_t)d * 2048 + p] = f2bf(val);
  }
}

// ---------- flash attention ----------
// grid (32 q-tiles, 24 bh), 256 threads = 4 waves; wave owns 16 q rows.
// Dk(cat)=192, Dv=64, KBLK=64, online softmax in MFMA C-layout.
__global__ __launch_bounds__(256) void attn(
    const unsigned short* __restrict__ Qc, const unsigned short* __restrict__ Kc,
    const unsigned short* __restrict__ VT, unsigned short* __restrict__ Oe) {
  __shared__ unsigned short Ks[64 * 192];
  __shared__ unsigned short Vs[64 * 64];
  __shared__ unsigned short Ps[4][16 * 64];
  const int t = threadIdx.x, w = t >> 6, l = t & 63, lr = l & 15, lg = l >> 4;
  const int bh = blockIdx.y, q0 = blockIdx.x * 64;
  const int b = bh / 12, h = bh - b * 12;
  const unsigned short* Qb = Qc + (size_t)bh * 2048 * 192;
  const unsigned short* Kb = Kc + (size_t)bh * 2048 * 192;
  const unsigned short* Vb = VT + (size_t)bh * 64 * 2048;

  v8bf qf[6];
  const int qrow = q0 + w * 16 + lr;
#pragma unroll
  for (int ks = 0; ks < 6; ++ks)
    qf[ks] = *(const v8bf*)(Qb + (size_t)qrow * 192 + ks * 32 + lg * 8);

  f32x4 o[4] = {};
  float mrow[4], lrow[4];
#pragma unroll
  for (int j = 0; j < 4; j++) { mrow[j] = -1e30f; lrow[j] = 0.f; }

  for (int kt = 0; kt < 32; ++kt) {
    // stage K tile (contiguous 24576 B)
#pragma unroll
    for (int i = 0; i < 6; i++) {
      int c = t + i * 256;
      gll16(Kb + (size_t)kt * 64 * 192 + c * 8, &Ks[c * 8]);
    }
    // stage V^T tile [64 d][64 keys]
#pragma unroll
    for (int i = 0; i < 2; i++) {
      int c = t + i * 256;
      int d = c >> 3, part = c & 7;
      gll16(Vb + (size_t)d * 2048 + kt * 64 + part * 8, &Vs[c * 8]);
    }
    __syncthreads();

    // S = Q K^T (scale pre-folded into Q)
    f32x4 s[4] = {};
#pragma unroll
    for (int nf = 0; nf < 4; nf++) {
#pragma unroll
      for (int ks = 0; ks < 6; ks++) {
        v8bf bfrag = *(const v8bf*)&Ks[(nf * 16 + lr) * 192 + ks * 32 + lg * 8];
        s[nf] = __builtin_amdgcn_mfma_f32_16x16x32_bf16(qf[ks], bfrag, s[nf], 0, 0, 0);
      }
    }

    // online softmax (rows live as (lg*4+j), cols as lr across 16-lane groups)
    float alpha[4];
#pragma unroll
    for (int j = 0; j < 4; j++) {
      float mv = fmaxf(fmaxf(s[0][j], s[1][j]), fmaxf(s[2][j], s[3][j]));
      mv = fmaxf(mv, __shfl_xor(mv, 1));
      mv = fmaxf(mv, __shfl_xor(mv, 2));
      mv = fmaxf(mv, __shfl_xor(mv, 4));
      mv = fmaxf(mv, __shfl_xor(mv, 8));
      float mnew = fmaxf(mrow[j], mv);
      alpha[j] = __builtin_exp2f((mrow[j] - mnew) * LOG2E);
      mrow[j] = mnew;
    }
    float psum[4] = {0.f, 0.f, 0.f, 0.f};
    unsigned short pb[4][4];
#pragma unroll
    for (int nf = 0; nf < 4; nf++) {
#pragma unroll
      for (int j = 0; j < 4; j++) {
        float p = __builtin_exp2f((s[nf][j] - mrow[j]) * LOG2E);
        psum[j] += p;
        pb[nf][j] = f2bf(p);
      }
    }
#pragma unroll
    for (int j = 0; j < 4; j++) {
      float ps = psum[j];
      ps += __shfl_xor(ps, 1);
      ps += __shfl_xor(ps, 2);
      ps += __shfl_xor(ps, 4);
      ps += __shfl_xor(ps, 8);
      lrow[j] = lrow[j] * alpha[j] + ps;
      o[0][j] *= alpha[j]; o[1][j] *= alpha[j]; o[2][j] *= alpha[j]; o[3][j] *= alpha[j];
    }

    // P -> LDS (re-layout C-frag -> A-frag)
#pragma unroll
    for (int nf = 0; nf < 4; nf++)
#pragma unroll
      for (int j = 0; j < 4; j++)
        Ps[w][(lg * 4 + j) * 64 + nf * 16 + lr] = pb[nf][j];

    // O += P V   (B-operand rows are V^T rows)
    v8bf pa[2];
#pragma unroll
    for (int ks = 0; ks < 2; ks++)
      pa[ks] = *(const v8bf*)&Ps[w][lr * 64 + ks * 32 + lg * 8];
#pragma unroll
    for (int df = 0; df < 4; df++) {
#pragma unroll
      for (int ks = 0; ks < 2; ks++) {
        v8bf vb2 = *(const v8bf*)&Vs[(df * 16 + lr) * 64 + ks * 32 + lg * 8];
        o[df] = __builtin_amdgcn_mfma_f32_16x16x32_bf16(pa[ks], vb2, o[df], 0, 0, 0);
      }
    }
    __syncthreads();
  }

  // epilogue: Oe[b*2048+q][h*64+d] = o / l
#pragma unroll
  for (int df = 0; df < 4; df++) {
#pragma unroll
    for (int j = 0; j < 4; j++) {
      int q = q0 + w * 16 + lg * 4 + j;
      int m = b * 2048 + q;
      int dcol = h * 64 + df * 16 + lr;
      Oe[(size_t)m * 768 + dcol] = f2bf(o[df][j] / lrow[j]);
    }
  }
}

// ---------- launcher ----------
extern "C" void kernel_launch(void* const* d_in, const int* in_sizes, int n_in,
                              void* d_out, int out_size, void* d_ws, size_t ws_size,
                              hipStream_t stream) {
  const float* x    = (const float*)d_in[0];
  const float* Wqkv = (const float*)d_in[1];
  const float* bqkv = (const float*)d_in[2];
  const float* Wout = (const float*)d_in[3];
  const float* bout = (const float*)d_in[4];
  float* out = (float*)d_out;
  char* ws = (char*)d_ws;

  unsigned short* Acat  = (unsigned short*)(ws + 0);          // 18.9 MB
  unsigned short* BcatT = (unsigned short*)(ws + 18874368);   // 10.6 MB
  float*          QKV   = (float*)(ws + 29491200);            // 37.7 MB
  unsigned short* Qcat  = (unsigned short*)(ws + 67239936);   // 18.9 MB
  unsigned short* Kcat  = (unsigned short*)(ws + 86114304);   // 18.9 MB
  unsigned short* VT    = (unsigned short*)(ws + 104988672);  //  6.3 MB
  unsigned short* Oemb  = (unsigned short*)(ws + 111280128);  //  6.3 MB
  unsigned short* WoutT = (unsigned short*)(ws + 117571584);  //  1.2 MB

  prep_a   <<<dim3(3, 4096), 256, 0, stream>>>(x, Acat);
  prep_bqkv<<<dim3(3, 2304), 256, 0, stream>>>(Wqkv, BcatT);
  prep_wout<<<dim3(3, 768),  256, 0, stream>>>(Wout, WoutT);
  gemm_bf16_128<<<dim3(18, 32), 256, 0, stream>>>(Acat, BcatT, bqkv, QKV, 4096, 2304, 2304);
  split_qkv<<<dim3(9, 4096), 256, 0, stream>>>(QKV, Qcat, Kcat, VT);
  attn<<<dim3(32, 24), 256, 0, stream>>>(Qcat, Kcat, VT, Oemb);
  gemm_bf16_128<<<dim3(6, 32), 256, 0, stream>>>(Oemb, WoutT, bout, out, 4096, 768, 768);
}

// Round 2
// 297.162 us; speedup vs baseline: 1.0395x; 1.0395x over previous
//
#include <hip/hip_runtime.h>
#include <stdint.h>

#define LOG2E 1.44269504088896340736f

typedef __bf16 v8bf __attribute__((ext_vector_type(8)));
typedef float f32x4 __attribute__((ext_vector_type(4)));

// ---------- helpers ----------
__device__ __forceinline__ unsigned short f2bf(float f) {
  union { float f; uint32_t u; } v; v.f = f;
  uint32_t u = v.u;
  uint32_t r = (u + 0x7FFFu + ((u >> 16) & 1u)) >> 16;   // RN-even
  return (unsigned short)r;
}
__device__ __forceinline__ float bf2f(unsigned short h) {
  union { uint32_t u; float f; } v; v.u = ((uint32_t)h) << 16;
  return v.f;
}
__device__ __forceinline__ void gll16(const void* g, void* l) {
  __builtin_amdgcn_global_load_lds(
      (const __attribute__((address_space(1))) unsigned int*)g,
      (__attribute__((address_space(3))) unsigned int*)l, 16, 0, 0);
}

// ---------- prep: x -> [hi | lo | hi]  (4096 x 2304 bf16) ----------
__global__ void prep_a(const float* __restrict__ x, unsigned short* __restrict__ Acat) {
  int n = blockIdx.x * 256 + threadIdx.x;   // 0..767
  int m = blockIdx.y;                       // 0..4095
  float v = x[(size_t)m * 768 + n];
  unsigned short H = f2bf(v);
  unsigned short L = f2bf(v - bf2f(H));
  size_t base = (size_t)m * 2304;
  Acat[base + n] = H;
  Acat[base + 768 + n] = L;
  Acat[base + 1536 + n] = H;
}

// ---------- prep: Wqkv^T cat -> rows n: [Whi | Whi | Wlo] (2304 x 2304 bf16) ----------
__global__ void prep_bqkv(const float* __restrict__ W, unsigned short* __restrict__ BT) {
  int k = blockIdx.x * 256 + threadIdx.x;   // 0..767
  int n = blockIdx.y;                       // 0..2303
  float v = W[(size_t)k * 2304 + n];
  unsigned short H = f2bf(v);
  unsigned short L = f2bf(v - bf2f(H));
  size_t base = (size_t)n * 2304;
  BT[base + k] = H;
  BT[base + 768 + k] = H;
  BT[base + 1536 + k] = L;
}

// ---------- prep: Wout^T single bf16 (768 x 768) ----------
__global__ void prep_wout(const float* __restrict__ W, unsigned short* __restrict__ BT) {
  int k = blockIdx.x * 256 + threadIdx.x;   // 0..767
  int n = blockIdx.y;                       // 0..767
  BT[(size_t)n * 768 + k] = f2bf(W[(size_t)k * 768 + n]);
}

// ---------- GEMM: C[M,N] = A[M,K](bf16) * B^T[N,K](bf16) + bias[N], fp32 out ----------
// 128x128 tile, BK=32, 256 threads (4 waves, each 64x64), mfma_f32_16x16x32_bf16
// NOTE: As/Bs reads at 64B row stride are already bank-quad-uniform (quad =
// 4*(row&1)+lg covers all 8) -> no swizzle needed here.
__global__ __launch_bounds__(256) void gemm_bf16_128(
    const unsigned short* __restrict__ A, const unsigned short* __restrict__ B,
    const float* __restrict__ bias, float* __restrict__ C,
    int M, int N, int K) {
  __shared__ unsigned short As[128 * 32];
  __shared__ unsigned short Bs[128 * 32];
  const int t = threadIdx.x;
  const int m0 = blockIdx.y * 128, n0 = blockIdx.x * 128;
  const int w = t >> 6, l = t & 63;
  const int wm = (w >> 1) * 64, wn = (w & 1) * 64;
  const int lr = l & 15, lg = l >> 4;
  f32x4 acc[4][4] = {};
  const int nk = K >> 5;
  for (int kt = 0; kt < nk; ++kt) {
    const int k0 = kt << 5;
    {
      const int c0 = t, c1 = t + 256;
      gll16(A + (size_t)(m0 + (c0 >> 2)) * K + k0 + ((c0 & 3) << 3), &As[c0 * 8]);
      gll16(A + (size_t)(m0 + (c1 >> 2)) * K + k0 + ((c1 & 3) << 3), &As[c1 * 8]);
      gll16(B + (size_t)(n0 + (c0 >> 2)) * K + k0 + ((c0 & 3) << 3), &Bs[c0 * 8]);
      gll16(B + (size_t)(n0 + (c1 >> 2)) * K + k0 + ((c1 & 3) << 3), &Bs[c1 * 8]);
    }
    __syncthreads();
    v8bf a[4], b[4];
#pragma unroll
    for (int i = 0; i < 4; i++) {
      a[i] = *(const v8bf*)&As[(wm + i * 16 + lr) * 32 + lg * 8];
      b[i] = *(const v8bf*)&Bs[(wn + i * 16 + lr) * 32 + lg * 8];
    }
#pragma unroll
    for (int i = 0; i < 4; i++)
#pragma unroll
      for (int j = 0; j < 4; j++)
        acc[i][j] = __builtin_amdgcn_mfma_f32_16x16x32_bf16(a[i], b[j], acc[i][j], 0, 0, 0);
    __syncthreads();
  }
#pragma unroll
  for (int i = 0; i < 4; i++) {
#pragma unroll
    for (int j = 0; j < 4; j++) {
      const int col = n0 + wn + j * 16 + lr;
      const float bv = bias[col];
#pragma unroll
      for (int r = 0; r < 4; r++) {
        const int row = m0 + wm + i * 16 + lg * 4 + r;
        C[(size_t)row * N + col] = acc[i][j][r] + bv;
      }
    }
  }
}

// ---------- split qkv fp32 -> Qcat/Kcat (split-bf16, *8 folded into Q), V^T bf16 ----------
__global__ void split_qkv(const float* __restrict__ qkv,
                          unsigned short* __restrict__ Qc,
                          unsigned short* __restrict__ Kc,
                          unsigned short* __restrict__ VT) {
  int n = blockIdx.x * 256 + threadIdx.x;   // 0..2303
  int m = blockIdx.y;                       // 0..4095
  float val = qkv[(size_t)m * 2304 + n];
  int h = n / 192;
  int j = n - h * 192;
  int b = m >> 11, p = m & 2047;
  int bh = b * 12 + h;
  size_t base = (size_t)bh * 2048 * 192 + (size_t)p * 192;
  if (j < 64) {
    float v8v = val * 8.0f;                 // fold logits *= sqrt(64) (exact: pow2)
    unsigned short H = f2bf(v8v);
    unsigned short L = f2bf(v8v - bf2f(H));
    Qc[base + j] = H; Qc[base + 64 + j] = L; Qc[base + 128 + j] = H;
  } else if (j < 128) {
    int d = j - 64;
    unsigned short H = f2bf(val);
    unsigned short L = f2bf(val - bf2f(H));
    Kc[base + d] = H; Kc[base + 64 + d] = H; Kc[base + 128 + d] = L;
  } else {
    int d = j - 128;
    VT[(size_t)bh * 64 * 2048 + (size_t)d * 2048 + p] = f2bf(val);
  }
}

// ---------- flash attention ----------
// grid (32 q-tiles, 24 bh), 256 threads = 4 waves; wave owns 16 q rows.
// Dk(cat)=192, Dv=64, KBLK=64, online softmax in MFMA C-layout.
// All LDS tiles XOR-swizzled: byte bits 4-6 ^= (row&7). Row strides (384/128/128 B)
// are multiples of 128 B so bits 4-6 are pure within-row bits -> bijective.
// global_load_lds writes stay LINEAR; the swizzle is applied to the GLOBAL
// source address (rule: both-sides-or-neither), and to every LDS read.
__global__ __launch_bounds__(256) void attn(
    const unsigned short* __restrict__ Qc, const unsigned short* __restrict__ Kc,
    const unsigned short* __restrict__ VT, unsigned short* __restrict__ Oe) {
  __shared__ unsigned short Ks[64 * 192];
  __shared__ unsigned short Vs[64 * 64];
  __shared__ unsigned short Ps[4][16 * 64];
  const int t = threadIdx.x, w = t >> 6, l = t & 63, lr = l & 15, lg = l >> 4;
  const int bh = blockIdx.y, q0 = blockIdx.x * 64;
  const int b = bh / 12, h = bh - b * 12;
  const unsigned short* Qb = Qc + (size_t)bh * 2048 * 192;
  const unsigned short* Kb = Kc + (size_t)bh * 2048 * 192;
  const unsigned short* Vb = VT + (size_t)bh * 64 * 2048;

  v8bf qf[6];
  const int qrow = q0 + w * 16 + lr;
#pragma unroll
  for (int ks = 0; ks < 6; ++ks)
    qf[ks] = *(const v8bf*)(Qb + (size_t)qrow * 192 + ks * 32 + lg * 8);

  f32x4 o[4] = {};
  float mrow[4], lrow[4];
#pragma unroll
  for (int j = 0; j < 4; j++) { mrow[j] = -1e30f; lrow[j] = 0.f; }

  const int sx = (lr & 7) << 3;   // read-side swizzle for rows == (16k + lr)

  for (int kt = 0; kt < 32; ++kt) {
    // stage K tile (contiguous 24576 B); source pre-swizzled, LDS dest linear
#pragma unroll
    for (int i = 0; i < 6; i++) {
      int c = t + i * 256;
      int row = c / 24;                              // 384 B/row = 24 x 16B chunks
      int src = (c * 8) ^ ((row & 7) << 3);
      gll16(Kb + (size_t)kt * 64 * 192 + src, &Ks[c * 8]);
    }
    // stage V^T tile [64 d][64 keys]; per-row 128 B, source chunk permuted
#pragma unroll
    for (int i = 0; i < 2; i++) {
      int c = t + i * 256;
      int d = c >> 3, part = c & 7;
      gll16(Vb + (size_t)d * 2048 + kt * 64 + ((part ^ (d & 7)) << 3), &Vs[c * 8]);
    }
    __syncthreads();

    // S = Q K^T (scale pre-folded into Q)
    f32x4 s[4] = {};
#pragma unroll
    for (int nf = 0; nf < 4; nf++) {
#pragma unroll
      for (int ks = 0; ks < 6; ks++) {
        v8bf bfrag = *(const v8bf*)&Ks[(((nf * 16 + lr) * 192) + ks * 32 + lg * 8) ^ sx];
        s[nf] = __builtin_amdgcn_mfma_f32_16x16x32_bf16(qf[ks], bfrag, s[nf], 0, 0, 0);
      }
    }

    // online softmax (rows live as (lg*4+j), cols as lr across 16-lane groups)
    float alpha[4];
#pragma unroll
    for (int j = 0; j < 4; j++) {
      float mv = fmaxf(fmaxf(s[0][j], s[1][j]), fmaxf(s[2][j], s[3][j]));
      mv = fmaxf(mv, __shfl_xor(mv, 1));
      mv = fmaxf(mv, __shfl_xor(mv, 2));
      mv = fmaxf(mv, __shfl_xor(mv, 4));
      mv = fmaxf(mv, __shfl_xor(mv, 8));
      float mnew = fmaxf(mrow[j], mv);
      alpha[j] = __builtin_exp2f((mrow[j] - mnew) * LOG2E);
      mrow[j] = mnew;
    }
    float psum[4] = {0.f, 0.f, 0.f, 0.f};
    unsigned short pb[4][4];
#pragma unroll
    for (int nf = 0; nf < 4; nf++) {
#pragma unroll
      for (int j = 0; j < 4; j++) {
        float p = __builtin_exp2f((s[nf][j] - mrow[j]) * LOG2E);
        psum[j] += p;
        pb[nf][j] = f2bf(p);
      }
    }
#pragma unroll
    for (int j = 0; j < 4; j++) {
      float ps = psum[j];
      ps += __shfl_xor(ps, 1);
      ps += __shfl_xor(ps, 2);
      ps += __shfl_xor(ps, 4);
      ps += __shfl_xor(ps, 8);
      lrow[j] = lrow[j] * alpha[j] + ps;
      o[0][j] *= alpha[j]; o[1][j] *= alpha[j]; o[2][j] *= alpha[j]; o[3][j] *= alpha[j];
    }

    // P -> LDS (re-layout C-frag -> A-frag), swizzled store
#pragma unroll
    for (int nf = 0; nf < 4; nf++)
#pragma unroll
      for (int j = 0; j < 4; j++) {
        int row = lg * 4 + j;
        Ps[w][((row * 64) + nf * 16 + lr) ^ ((row & 7) << 3)] = pb[nf][j];
      }

    // O += P V   (B-operand rows are V^T rows), swizzled reads
    v8bf pa[2];
#pragma unroll
    for (int ks = 0; ks < 2; ks++)
      pa[ks] = *(const v8bf*)&Ps[w][((lr * 64) + ks * 32 + lg * 8) ^ sx];
#pragma unroll
    for (int df = 0; df < 4; df++) {
#pragma unroll
      for (int ks = 0; ks < 2; ks++) {
        v8bf vb2 = *(const v8bf*)&Vs[(((df * 16 + lr) * 64) + ks * 32 + lg * 8) ^ sx];
        o[df] = __builtin_amdgcn_mfma_f32_16x16x32_bf16(pa[ks], vb2, o[df], 0, 0, 0);
      }
    }
    __syncthreads();
  }

  // epilogue: Oe[b*2048+q][h*64+d] = o / l
#pragma unroll
  for (int df = 0; df < 4; df++) {
#pragma unroll
    for (int j = 0; j < 4; j++) {
      int q = q0 + w * 16 + lg * 4 + j;
      int m = b * 2048 + q;
      int dcol = h * 64 + df * 16 + lr;
      Oe[(size_t)m * 768 + dcol] = f2bf(o[df][j] / lrow[j]);
    }
  }
}

// ---------- launcher ----------
extern "C" void kernel_launch(void* const* d_in, const int* in_sizes, int n_in,
                              void* d_out, int out_size, void* d_ws, size_t ws_size,
                              hipStream_t stream) {
  const float* x    = (const float*)d_in[0];
  const float* Wqkv = (const float*)d_in[1];
  const float* bqkv = (const float*)d_in[2];
  const float* Wout = (const float*)d_in[3];
  const float* bout = (const float*)d_in[4];
  float* out = (float*)d_out;
  char* ws = (char*)d_ws;

  unsigned short* Acat  = (unsigned short*)(ws + 0);          // 18.9 MB
  unsigned short* BcatT = (unsigned short*)(ws + 18874368);   // 10.6 MB
  float*          QKV   = (float*)(ws + 29491200);            // 37.7 MB
  unsigned short* Qcat  = (unsigned short*)(ws + 67239936);   // 18.9 MB
  unsigned short* Kcat  = (unsigned short*)(ws + 86114304);   // 18.9 MB
  unsigned short* VT    = (unsigned short*)(ws + 104988672);  //  6.3 MB
  unsigned short* Oemb  = (unsigned short*)(ws + 111280128);  //  6.3 MB
  unsigned short* WoutT = (unsigned short*)(ws + 117571584);  //  1.2 MB

  prep_a   <<<dim3(3, 4096), 256, 0, stream>>>(x, Acat);
  prep_bqkv<<<dim3(3, 2304), 256, 0, stream>>>(Wqkv, BcatT);
  prep_wout<<<dim3(3, 768),  256, 0, stream>>>(Wout, WoutT);
  gemm_bf16_128<<<dim3(18, 32), 256, 0, stream>>>(Acat, BcatT, bqkv, QKV, 4096, 2304, 2304);
  split_qkv<<<dim3(9, 4096), 256, 0, stream>>>(QKV, Qcat, Kcat, VT);
  attn<<<dim3(32, 24), 256, 0, stream>>>(Qcat, Kcat, VT, Oemb);
  gemm_bf16_128<<<dim3(6, 32), 256, 0, stream>>>(Oemb, WoutT, bout, out, 4096, 768, 768);
}

// Round 3
// 275.759 us; speedup vs baseline: 1.1202x; 1.0776x over previous
//
#include <hip/hip_runtime.h>
#include <stdint.h>

#define LOG2E 1.44269504088896340736f

typedef __bf16 v8bf __attribute__((ext_vector_type(8)));
typedef float f32x4 __attribute__((ext_vector_type(4)));
typedef unsigned int v4u __attribute__((ext_vector_type(4)));

// ---------- helpers ----------
__device__ __forceinline__ unsigned short f2bf(float f) {
  union { float f; uint32_t u; } v; v.f = f;
  uint32_t u = v.u;
  uint32_t r = (u + 0x7FFFu + ((u >> 16) & 1u)) >> 16;   // RN-even
  return (unsigned short)r;
}
__device__ __forceinline__ float bf2f(unsigned short h) {
  union { uint32_t u; float f; } v; v.u = ((uint32_t)h) << 16;
  return v.f;
}
__device__ __forceinline__ void gll16(const void* g, void* l) {
  __builtin_amdgcn_global_load_lds(
      (const __attribute__((address_space(1))) unsigned int*)g,
      (__attribute__((address_space(3))) unsigned int*)l, 16, 0, 0);
}

// ---------- prep: x -> [hi | lo | hi]  (4096 x 2304 bf16) ----------
__global__ void prep_a(const float* __restrict__ x, unsigned short* __restrict__ Acat) {
  int n = blockIdx.x * 256 + threadIdx.x;   // 0..767
  int m = blockIdx.y;                       // 0..4095
  float v = x[(size_t)m * 768 + n];
  unsigned short H = f2bf(v);
  unsigned short L = f2bf(v - bf2f(H));
  size_t base = (size_t)m * 2304;
  Acat[base + n] = H;
  Acat[base + 768 + n] = L;
  Acat[base + 1536 + n] = H;
}

// ---------- prep: Wqkv^T cat -> rows n: [Whi | Whi | Wlo] (2304 x 2304 bf16) ----------
__global__ void prep_bqkv(const float* __restrict__ W, unsigned short* __restrict__ BT) {
  int k = blockIdx.x * 256 + threadIdx.x;   // 0..767
  int n = blockIdx.y;                       // 0..2303
  float v = W[(size_t)k * 2304 + n];
  unsigned short H = f2bf(v);
  unsigned short L = f2bf(v - bf2f(H));
  size_t base = (size_t)n * 2304;
  BT[base + k] = H;
  BT[base + 768 + k] = H;
  BT[base + 1536 + k] = L;
}

// ---------- prep: Wout^T single bf16 (768 x 768) ----------
__global__ void prep_wout(const float* __restrict__ W, unsigned short* __restrict__ BT) {
  int k = blockIdx.x * 256 + threadIdx.x;   // 0..767
  int n = blockIdx.y;                       // 0..767
  BT[(size_t)n * 768 + k] = f2bf(W[(size_t)k * 768 + n]);
}

// ---------- GEMM: C[M,N] = A[M,K](bf16) * B^T[N,K](bf16) + bias[N], fp32 out ----------
// 128x128 tile, BK=32, 256 threads (4 waves, each 64x64), mfma_f32_16x16x32_bf16
__global__ __launch_bounds__(256) void gemm_bf16_128(
    const unsigned short* __restrict__ A, const unsigned short* __restrict__ B,
    const float* __restrict__ bias, float* __restrict__ C,
    int M, int N, int K) {
  __shared__ unsigned short As[128 * 32];
  __shared__ unsigned short Bs[128 * 32];
  const int t = threadIdx.x;
  const int m0 = blockIdx.y * 128, n0 = blockIdx.x * 128;
  const int w = t >> 6, l = t & 63;
  const int wm = (w >> 1) * 64, wn = (w & 1) * 64;
  const int lr = l & 15, lg = l >> 4;
  f32x4 acc[4][4] = {};
  const int nk = K >> 5;
  for (int kt = 0; kt < nk; ++kt) {
    const int k0 = kt << 5;
    {
      const int c0 = t, c1 = t + 256;
      gll16(A + (size_t)(m0 + (c0 >> 2)) * K + k0 + ((c0 & 3) << 3), &As[c0 * 8]);
      gll16(A + (size_t)(m0 + (c1 >> 2)) * K + k0 + ((c1 & 3) << 3), &As[c1 * 8]);
      gll16(B + (size_t)(n0 + (c0 >> 2)) * K + k0 + ((c0 & 3) << 3), &Bs[c0 * 8]);
      gll16(B + (size_t)(n0 + (c1 >> 2)) * K + k0 + ((c1 & 3) << 3), &Bs[c1 * 8]);
    }
    __syncthreads();
    v8bf a[4], b[4];
#pragma unroll
    for (int i = 0; i < 4; i++) {
      a[i] = *(const v8bf*)&As[(wm + i * 16 + lr) * 32 + lg * 8];
      b[i] = *(const v8bf*)&Bs[(wn + i * 16 + lr) * 32 + lg * 8];
    }
#pragma unroll
    for (int i = 0; i < 4; i++)
#pragma unroll
      for (int j = 0; j < 4; j++)
        acc[i][j] = __builtin_amdgcn_mfma_f32_16x16x32_bf16(a[i], b[j], acc[i][j], 0, 0, 0);
    __syncthreads();
  }
#pragma unroll
  for (int i = 0; i < 4; i++) {
#pragma unroll
    for (int j = 0; j < 4; j++) {
      const int col = n0 + wn + j * 16 + lr;
      const float bv = bias[col];
#pragma unroll
      for (int r = 0; r < 4; r++) {
        const int row = m0 + wm + i * 16 + lg * 4 + r;
        C[(size_t)row * N + col] = acc[i][j][r] + bv;
      }
    }
  }
}

// ---------- split qkv fp32 -> Qcat/Kcat (split-bf16, *8 folded into Q), V^T bf16 ----------
__global__ void split_qkv(const float* __restrict__ qkv,
                          unsigned short* __restrict__ Qc,
                          unsigned short* __restrict__ Kc,
                          unsigned short* __restrict__ VT) {
  int n = blockIdx.x * 256 + threadIdx.x;   // 0..2303
  int m = blockIdx.y;                       // 0..4095
  float val = qkv[(size_t)m * 2304 + n];
  int h = n / 192;
  int j = n - h * 192;
  int b = m >> 11, p = m & 2047;
  int bh = b * 12 + h;
  size_t base = (size_t)bh * 2048 * 192 + (size_t)p * 192;
  if (j < 64) {
    float v8v = val * 8.0f;                 // fold logits *= sqrt(64) (exact: pow2)
    unsigned short H = f2bf(v8v);
    unsigned short L = f2bf(v8v - bf2f(H));
    Qc[base + j] = H; Qc[base + 64 + j] = L; Qc[base + 128 + j] = H;
  } else if (j < 128) {
    int d = j - 64;
    unsigned short H = f2bf(val);
    unsigned short L = f2bf(val - bf2f(H));
    Kc[base + d] = H; Kc[base + 64 + d] = H; Kc[base + 128 + d] = L;
  } else {
    int d = j - 128;
    VT[(size_t)bh * 64 * 2048 + (size_t)d * 2048 + p] = f2bf(val);
  }
}

// ---------- flash attention ----------
// grid (32 q-tiles, 24 bh), 256 threads = 4 waves; wave owns 16 q rows.
// Dk(cat)=192, Dv=64, KBLK=64, online softmax in MFMA C-layout.
// T14 async-STAGE: global->reg loads issued right after the post-write barrier
// (fly during compute of the current tile); ds_write at top of next iter.
// Global sources LINEAR (pointer-bump); swizzle applied on ds_write AND ds_read:
// element offset ^= (row&7)<<3 (byte bits 4-6) -> bank-quad-uniform b128 ops.
__global__ __launch_bounds__(256) void attn(
    const unsigned short* __restrict__ Qc, const unsigned short* __restrict__ Kc,
    const unsigned short* __restrict__ VT, __bf16* __restrict__ Oe) {
  __shared__ __align__(16) unsigned short Ks[64 * 192];
  __shared__ __align__(16) unsigned short Vs[64 * 64];
  __shared__ __align__(16) __bf16 Ps[4][16 * 64];
  const int t = threadIdx.x, w = t >> 6, l = t & 63, lr = l & 15, lg = l >> 4;
  const int bh = blockIdx.y, q0 = blockIdx.x * 64;
  const int b = bh / 12, h = bh - b * 12;
  const unsigned short* Qb = Qc + (size_t)bh * 2048 * 192;
  const unsigned short* Kb = Kc + (size_t)bh * 2048 * 192;
  const unsigned short* Vb = VT + (size_t)bh * 64 * 2048;

  // hoisted LDS write offsets (element units), swizzled
  int kwofs[6];
#pragma unroll
  for (int i = 0; i < 6; i++) {
    int c = t + i * 256;                    // 16B chunk id; 24 chunks per 192-elem row
    int row = c / 24, cc = c - row * 24;
    kwofs[i] = (row * 192 + cc * 8) ^ ((row & 7) << 3);
  }
  int vwofs[2];
#pragma unroll
  for (int i = 0; i < 2; i++) {
    int c = t + i * 256;                    // 8 chunks per 64-elem V^T row
    int d = c >> 3, part = c & 7;
    vwofs[i] = (d * 64 + part * 8) ^ ((d & 7) << 3);
  }
  // linear global source pointers (coalesced), bumped per kt
  const char* gK = (const char*)Kb + (size_t)t * 16;                       // +24576 B per kt
  const char* gV = (const char*)Vb + (size_t)(t >> 3) * 4096 + (size_t)(t & 7) * 16;  // +128 B per kt

  v4u kreg[6], vreg[2];
#pragma unroll
  for (int i = 0; i < 6; i++) kreg[i] = *(const v4u*)(gK + i * 4096);
#pragma unroll
  for (int i = 0; i < 2; i++) vreg[i] = *(const v4u*)(gV + i * 131072);

  v8bf qf[6];
  const int qrow = q0 + w * 16 + lr;
#pragma unroll
  for (int ks = 0; ks < 6; ++ks)
    qf[ks] = *(const v8bf*)(Qb + (size_t)qrow * 192 + ks * 32 + lg * 8);

  f32x4 o[4] = {};
  float mrow[4], lrow[4];
#pragma unroll
  for (int j = 0; j < 4; j++) { mrow[j] = -1e30f; lrow[j] = 0.f; }

  const int sx = (lr & 7) << 3;   // read-side swizzle for rows == (16k + lr)

  for (int kt = 0; kt < 32; ++kt) {
    // drain staged regs to LDS (compiler inserts vmcnt waits on first use)
#pragma unroll
    for (int i = 0; i < 6; i++) *(v4u*)&Ks[kwofs[i]] = kreg[i];
#pragma unroll
    for (int i = 0; i < 2; i++) *(v4u*)&Vs[vwofs[i]] = vreg[i];
    __syncthreads();

    // issue next tile's loads — in flight during this tile's compute
    if (kt < 31) {
      gK += 24576; gV += 128;
#pragma unroll
      for (int i = 0; i < 6; i++) kreg[i] = *(const v4u*)(gK + i * 4096);
#pragma unroll
      for (int i = 0; i < 2; i++) vreg[i] = *(const v4u*)(gV + i * 131072);
    }

    // S = Q K^T (scale pre-folded into Q)
    f32x4 s[4] = {};
#pragma unroll
    for (int nf = 0; nf < 4; nf++) {
#pragma unroll
      for (int ks = 0; ks < 6; ks++) {
        v8bf bfrag = *(const v8bf*)&Ks[(((nf * 16 + lr) * 192) + ks * 32 + lg * 8) ^ sx];
        s[nf] = __builtin_amdgcn_mfma_f32_16x16x32_bf16(qf[ks], bfrag, s[nf], 0, 0, 0);
      }
    }

    // online softmax (rows live as (lg*4+j), cols as lr across 16-lane groups)
    float alpha[4];
#pragma unroll
    for (int j = 0; j < 4; j++) {
      float mv = fmaxf(fmaxf(s[0][j], s[1][j]), fmaxf(s[2][j], s[3][j]));
      mv = fmaxf(mv, __shfl_xor(mv, 1));
      mv = fmaxf(mv, __shfl_xor(mv, 2));
      mv = fmaxf(mv, __shfl_xor(mv, 4));
      mv = fmaxf(mv, __shfl_xor(mv, 8));
      float mnew = fmaxf(mrow[j], mv);
      alpha[j] = __builtin_exp2f((mrow[j] - mnew) * LOG2E);
      mrow[j] = mnew;
    }
    float psum[4] = {0.f, 0.f, 0.f, 0.f};
    __bf16 pb[4][4];
#pragma unroll
    for (int nf = 0; nf < 4; nf++) {
#pragma unroll
      for (int j = 0; j < 4; j++) {
        float p = __builtin_exp2f((s[nf][j] - mrow[j]) * LOG2E);
        psum[j] += p;
        pb[nf][j] = (__bf16)p;              // native cvt (pk-paired by compiler)
      }
    }
#pragma unroll
    for (int j = 0; j < 4; j++) {
      float ps = psum[j];
      ps += __shfl_xor(ps, 1);
      ps += __shfl_xor(ps, 2);
      ps += __shfl_xor(ps, 4);
      ps += __shfl_xor(ps, 8);
      lrow[j] = lrow[j] * alpha[j] + ps;
      o[0][j] *= alpha[j]; o[1][j] *= alpha[j]; o[2][j] *= alpha[j]; o[3][j] *= alpha[j];
    }

    // P -> LDS (re-layout C-frag -> A-frag), swizzled store
#pragma unroll
    for (int nf = 0; nf < 4; nf++)
#pragma unroll
      for (int j = 0; j < 4; j++) {
        int row = lg * 4 + j;
        Ps[w][((row * 64) + nf * 16 + lr) ^ ((row & 7) << 3)] = pb[nf][j];
      }

    // O += P V   (B-operand rows are V^T rows), swizzled reads
    v8bf pa[2];
#pragma unroll
    for (int ks = 0; ks < 2; ks++)
      pa[ks] = *(const v8bf*)&Ps[w][((lr * 64) + ks * 32 + lg * 8) ^ sx];
#pragma unroll
    for (int df = 0; df < 4; df++) {
#pragma unroll
      for (int ks = 0; ks < 2; ks++) {
        v8bf vb2 = *(const v8bf*)&Vs[(((df * 16 + lr) * 64) + ks * 32 + lg * 8) ^ sx];
        o[df] = __builtin_amdgcn_mfma_f32_16x16x32_bf16(pa[ks], vb2, o[df], 0, 0, 0);
      }
    }
    __syncthreads();
  }

  // epilogue: Oe[b*2048+q][h*64+d] = o / l
#pragma unroll
  for (int j = 0; j < 4; j++) {
    const float rinv = 1.0f / lrow[j];
    const int q = q0 + w * 16 + lg * 4 + j;
    const int m = b * 2048 + q;
#pragma unroll
    for (int df = 0; df < 4; df++) {
      const int dcol = h * 64 + df * 16 + lr;
      Oe[(size_t)m * 768 + dcol] = (__bf16)(o[df][j] * rinv);
    }
  }
}

// ---------- launcher ----------
extern "C" void kernel_launch(void* const* d_in, const int* in_sizes, int n_in,
                              void* d_out, int out_size, void* d_ws, size_t ws_size,
                              hipStream_t stream) {
  const float* x    = (const float*)d_in[0];
  const float* Wqkv = (const float*)d_in[1];
  const float* bqkv = (const float*)d_in[2];
  const float* Wout = (const float*)d_in[3];
  const float* bout = (const float*)d_in[4];
  float* out = (float*)d_out;
  char* ws = (char*)d_ws;

  unsigned short* Acat  = (unsigned short*)(ws + 0);          // 18.9 MB
  unsigned short* BcatT = (unsigned short*)(ws + 18874368);   // 10.6 MB
  float*          QKV   = (float*)(ws + 29491200);            // 37.7 MB
  unsigned short* Qcat  = (unsigned short*)(ws + 67239936);   // 18.9 MB
  unsigned short* Kcat  = (unsigned short*)(ws + 86114304);   // 18.9 MB
  unsigned short* VT    = (unsigned short*)(ws + 104988672);  //  6.3 MB
  unsigned short* Oemb  = (unsigned short*)(ws + 111280128);  //  6.3 MB
  unsigned short* WoutT = (unsigned short*)(ws + 117571584);  //  1.2 MB

  prep_a   <<<dim3(3, 4096), 256, 0, stream>>>(x, Acat);
  prep_bqkv<<<dim3(3, 2304), 256, 0, stream>>>(Wqkv, BcatT);
  prep_wout<<<dim3(3, 768),  256, 0, stream>>>(Wout, WoutT);
  gemm_bf16_128<<<dim3(18, 32), 256, 0, stream>>>(Acat, BcatT, bqkv, QKV, 4096, 2304, 2304);
  split_qkv<<<dim3(9, 4096), 256, 0, stream>>>(QKV, Qcat, Kcat, VT);
  attn<<<dim3(32, 24), 256, 0, stream>>>(Qcat, Kcat, VT, (__bf16*)Oemb);
  gemm_bf16_128<<<dim3(6, 32), 256, 0, stream>>>(Oemb, WoutT, bout, out, 4096, 768, 768);
}